// Round 13
// baseline (361.339 us; speedup 1.0000x reference)
//
#include <hip/hip_runtime.h>
#include <hip/hip_bf16.h>
#include <math.h>

#define N_TOK 32768
#define LC 16
#define NCHUNK (N_TOK / LC)   // 2048
#define NSEG 64
#define SEGLEN (NCHUNK / NSEG) // 32

typedef short short8 __attribute__((ext_vector_type(8)));   // 8 bf16 (4 VGPRs)
typedef float f32x4 __attribute__((ext_vector_type(4)));

__device__ __forceinline__ float siluf_(float v){ return v / (1.f + __expf(-v)); }
__device__ __forceinline__ float softplusf_(float v){ return v > 20.f ? v : log1pf(__expf(v)); }

__device__ __forceinline__ unsigned f2bfu(float f){
  __hip_bfloat16 h = __float2bfloat16(f);
  return (unsigned)*(unsigned short*)&h;
}
__device__ __forceinline__ float bfu2f(unsigned short u){
  __hip_bfloat16 h; *(unsigned short*)&h = u; return __bfloat162float(h);
}

__device__ __forceinline__ float waveRed64(float v){
  #pragma unroll
  for (int m = 1; m < 64; m <<= 1) v += __shfl_xor(v, m);
  return v;
}

// pw[s] = w^(s+1), 15 muls, depth 4
__device__ __forceinline__ void pow_chain(float w, float pw[16]){
  pw[0]=w; pw[1]=w*w; pw[2]=pw[1]*w; pw[3]=pw[1]*pw[1];
  pw[4]=pw[3]*pw[0]; pw[5]=pw[3]*pw[1]; pw[6]=pw[3]*pw[2]; pw[7]=pw[3]*pw[3];
  pw[8]=pw[7]*pw[0]; pw[9]=pw[7]*pw[1]; pw[10]=pw[7]*pw[2]; pw[11]=pw[7]*pw[3];
  pw[12]=pw[7]*pw[4]; pw[13]=pw[7]*pw[5]; pw[14]=pw[7]*pw[6]; pw[15]=pw[7]*pw[7];
}

__device__ __forceinline__ bool check_intA(const float aS[16]){
  bool ok = true;
  #pragma unroll
  for (int s=0;s<16;s++){
    float tgt = (float)(s+1);
    if (fabsf(-aS[s] - tgt) > 1e-4f*tgt) ok = false;
  }
  return ok;
}

// ---------- all weight converts in one launch ----------
__global__ void k_wcvt_all(const float* __restrict__ ipw, const float* __restrict__ opw,
                           const float* __restrict__ w1, const float* __restrict__ w2,
                           const float* __restrict__ xpw,
                           __hip_bfloat16* __restrict__ ipwt, __hip_bfloat16* __restrict__ opwt,
                           __hip_bfloat16* __restrict__ w1t, __hip_bfloat16* __restrict__ w2t,
                           __hip_bfloat16* __restrict__ xpwt){
  int e = blockIdx.x*256 + threadIdx.x;
  if (e < 65536){ int n=e>>7, k=e&127; ipwt[e]=__float2bfloat16(ipw[k*512+n]); }
  else if (e < 98304){ int f=e-65536; int n=f>>8, k=f&255; opwt[f]=__float2bfloat16(opw[k*128+n]); }
  else if (e < 131072){ int f=e-98304; int n=f>>8, k=f&255; w1t[f]=__float2bfloat16(w1[k*128+n]); }
  else if (e < 147456){ int f=e-131072; int n=f>>7, k=f&127; w2t[f]=__float2bfloat16(w2[k*128+n]); }
  else if (e < 159744){ int f=e-147456; int n=f>>8, k=f&255;
                        xpwt[f]=(n<40)?__float2bfloat16(xpw[k*40+n]):__float2bfloat16(0.f); }
}

// ---------- K1: fused rmsnorm(feat)->a0 AND gather+LN->cat[:,128:256] ----------
__global__ void k_gat_rms(const float* __restrict__ feat, const int* __restrict__ ridx,
                          const float* __restrict__ gd, const float* __restrict__ g,
                          const float* __restrict__ b, const float* __restrict__ rmsw,
                          unsigned* __restrict__ catu, unsigned* __restrict__ a0u){
  int row = blockIdx.x*4 + (threadIdx.x>>6);
  int lane = threadIdx.x & 63;
  float2 f2 = ((const float2*)feat)[row*64 + lane];
  float ss = waveRed64(f2.x*f2.x + f2.y*f2.y);
  float is0 = rsqrtf(ss * (1.f/128.f) + 1e-5f);
  float2 w = ((const float2*)rmsw)[lane];
  a0u[row*64 + lane] = f2bfu(f2.x*is0*w.x) | (f2bfu(f2.y*is0*w.y) << 16);
  float ax=0.f, ay=0.f;
  #pragma unroll 4
  for (int k=0;k<16;k++){
    int idx = ridx[row*16+k];
    float ww = gd[row*16+k];
    float2 f = ((const float2*)feat)[idx*64 + lane];
    ax += ww*f.x; ay += ww*f.y;
  }
  float m = waveRed64(ax+ay) * (1.f/128.f);
  float dx = ax-m, dy = ay-m;
  float var = waveRed64(dx*dx+dy*dy) * (1.f/128.f);
  float is = rsqrtf(var + 1e-5f);
  float2 gg = ((const float2*)g)[lane];
  float2 bb = ((const float2*)b)[lane];
  float ox = dx*is*gg.x + bb.x, oy = dy*is*gg.y + bb.y;
  catu[row*128 + 64 + lane] = f2bfu(ox) | (f2bfu(oy) << 16);
}

// ---------- MFMA GEMM: out[M,N] = A[M,K](bf16) @ Wt[N,K](bf16)^T ----------
// MODE 0: + bias? + resid? -> out0 (f32)
// MODE 1: n<256 -> out0b (x, bf16); n>=256 -> silu -> out1 (z, bf16 contiguous)
template<int WM16, int WN16, int MODE>
__global__ __launch_bounds__(256) void k_mfma(const __hip_bfloat16* __restrict__ A,
      const __hip_bfloat16* __restrict__ Wt, int K,
      const float* __restrict__ bias, const float* __restrict__ resid,
      float* __restrict__ out0, __hip_bfloat16* __restrict__ out0b,
      __hip_bfloat16* __restrict__ out1, int ldout){
  int tid = threadIdx.x;
  int wave = tid>>6, lane = tid&63;
  int wm = wave>>1, wn = wave&1;
  int lane16 = lane&15, quad = lane>>4;
  int m_w = blockIdx.x*(2*WM16*16) + wm*(WM16*16);
  int n_w = blockIdx.y*(2*WN16*16) + wn*(WN16*16);
  f32x4 acc[WM16][WN16];
  #pragma unroll
  for (int i=0;i<WM16;i++)
    #pragma unroll
    for (int j=0;j<WN16;j++) acc[i][j] = (f32x4){0.f,0.f,0.f,0.f};
  const __hip_bfloat16* Ab = A  + (size_t)(m_w + lane16)*K + quad*8;
  const __hip_bfloat16* Bb = Wt + (size_t)(n_w + lane16)*K + quad*8;
  #pragma unroll 4
  for (int kk=0; kk<K; kk+=32){
    short8 a[WM16], b[WN16];
    #pragma unroll
    for (int i=0;i<WM16;i++) a[i] = *(const short8*)(Ab + (size_t)i*16*K + kk);
    #pragma unroll
    for (int j=0;j<WN16;j++) b[j] = *(const short8*)(Bb + (size_t)j*16*K + kk);
    #pragma unroll
    for (int i=0;i<WM16;i++)
      #pragma unroll
      for (int j=0;j<WN16;j++)
        acc[i][j] = __builtin_amdgcn_mfma_f32_16x16x32_bf16(a[i], b[j], acc[i][j], 0, 0, 0);
  }
  #pragma unroll
  for (int i=0;i<WM16;i++){
    #pragma unroll
    for (int j=0;j<WN16;j++){
      int n = n_w + j*16 + lane16;
      float bv = 0.f;
      if (MODE==0 && bias) bv = bias[n];
      #pragma unroll
      for (int r=0;r<4;r++){
        int m = m_w + i*16 + quad*4 + r;
        float v = acc[i][j][r] + bv;
        if (MODE==0){
          if (resid) v += resid[(size_t)m*ldout + n];
          out0[(size_t)m*ldout + n] = v;
        } else {
          if (n < 256) out0b[(size_t)m*256 + n] = __float2bfloat16(v);
          else         out1[(size_t)m*256 + (n-256)] = __float2bfloat16(siluf_(v));
        }
      }
    }
  }
}

// ---------- fused MFMA + LayerNorm: tile 64x128 -> LDS -> rowwise LN -> bf16 ----------
template<int RELU>
__global__ __launch_bounds__(256) void k_mfma_ln(const __hip_bfloat16* __restrict__ A,
      const __hip_bfloat16* __restrict__ Wt, int K,
      const float* __restrict__ bias, const float* __restrict__ resid,
      const float* __restrict__ g, const float* __restrict__ b,
      unsigned* __restrict__ outu, int ldu){
  __shared__ float Ls[64][132];
  int tid = threadIdx.x;
  int wave = tid>>6, lane = tid&63;
  int wm = wave>>1, wn = wave&1;
  int lane16 = lane&15, quad = lane>>4;
  int r0 = blockIdx.x*64;
  int m_w = wm*32;
  int n_w = wn*64;
  f32x4 acc[2][4];
  #pragma unroll
  for (int i=0;i<2;i++)
    #pragma unroll
    for (int j=0;j<4;j++) acc[i][j] = (f32x4){0.f,0.f,0.f,0.f};
  const __hip_bfloat16* Ab = A  + (size_t)(r0 + m_w + lane16)*K + quad*8;
  const __hip_bfloat16* Bb = Wt + (size_t)(n_w + lane16)*K + quad*8;
  #pragma unroll 4
  for (int kk=0; kk<K; kk+=32){
    short8 a[2], bfr[4];
    #pragma unroll
    for (int i=0;i<2;i++) a[i] = *(const short8*)(Ab + (size_t)i*16*K + kk);
    #pragma unroll
    for (int j=0;j<4;j++) bfr[j] = *(const short8*)(Bb + (size_t)j*16*K + kk);
    #pragma unroll
    for (int i=0;i<2;i++)
      #pragma unroll
      for (int j=0;j<4;j++)
        acc[i][j] = __builtin_amdgcn_mfma_f32_16x16x32_bf16(a[i], bfr[j], acc[i][j], 0, 0, 0);
  }
  #pragma unroll
  for (int i=0;i<2;i++){
    #pragma unroll
    for (int j=0;j<4;j++){
      int n = n_w + j*16 + lane16;
      float bv = bias ? bias[n] : 0.f;
      #pragma unroll
      for (int r=0;r<4;r++){
        int m = m_w + i*16 + quad*4 + r;
        float v = acc[i][j][r] + bv;
        if (resid) v += resid[(size_t)(r0+m)*128 + n];
        Ls[m][n] = v;
      }
    }
  }
  __syncthreads();
  float2 gv = ((const float2*)g)[lane];
  float2 bv2 = ((const float2*)b)[lane];
  #pragma unroll 4
  for (int rr=0; rr<16; rr++){
    int row = wave*16 + rr;
    float2 v = *(const float2*)&Ls[row][2*lane];
    float mm = waveRed64(v.x+v.y) * (1.f/128.f);
    float dx = v.x-mm, dy = v.y-mm;
    float var = waveRed64(dx*dx+dy*dy) * (1.f/128.f);
    float is = rsqrtf(var + 1e-5f);
    float ox = dx*is*gv.x + bv2.x;
    float oy = dy*is*gv.y + bv2.y;
    if (RELU){ ox = fmaxf(ox, 0.f); oy = fmaxf(oy, 0.f); }
    outu[(size_t)(r0+row)*ldu + lane] = f2bfu(ox) | (f2bfu(oy) << 16);
  }
}

// ---------- xproj MFMA: dbc[M,48] = xb[M,256] @ xpwt[48,256]^T, split-store ----------
__global__ __launch_bounds__(256) void k_xproj_mfma(const __hip_bfloat16* __restrict__ A,
      const __hip_bfloat16* __restrict__ Wt,
      float* __restrict__ dt8, float* __restrict__ Bm, float* __restrict__ Cm){
  int tid = threadIdx.x;
  int wave = tid>>6, lane = tid&63;
  int lane16 = lane&15, quad = lane>>4;
  int m_w = blockIdx.x*64 + wave*16;
  f32x4 acc[3];
  #pragma unroll
  for (int j=0;j<3;j++) acc[j] = (f32x4){0.f,0.f,0.f,0.f};
  const __hip_bfloat16* Ab = A  + (size_t)(m_w + lane16)*256 + quad*8;
  const __hip_bfloat16* Bb = Wt + (size_t)lane16*256 + quad*8;
  #pragma unroll
  for (int kk=0; kk<256; kk+=32){
    short8 a = *(const short8*)(Ab + kk);
    short8 b0 = *(const short8*)(Bb + kk);
    short8 b1 = *(const short8*)(Bb + 16*256 + kk);
    short8 b2 = *(const short8*)(Bb + 32*256 + kk);
    acc[0] = __builtin_amdgcn_mfma_f32_16x16x32_bf16(a, b0, acc[0], 0, 0, 0);
    acc[1] = __builtin_amdgcn_mfma_f32_16x16x32_bf16(a, b1, acc[1], 0, 0, 0);
    acc[2] = __builtin_amdgcn_mfma_f32_16x16x32_bf16(a, b2, acc[2], 0, 0, 0);
  }
  #pragma unroll
  for (int j=0;j<3;j++){
    int n = j*16 + lane16;
    #pragma unroll
    for (int r=0;r<4;r++){
      int m = m_w + quad*4 + r;
      float v = acc[j][r];
      if (n < 8)       dt8[(size_t)m*8 + n] = v;
      else if (n < 24) Bm[(size_t)m*16 + (n-8)] = v;
      else if (n < 40) Cm[(size_t)m*16 + (n-24)] = v;
    }
  }
}

// ---------- K3: causal depthwise conv + silu, bf16 in/out ----------
__global__ void __launch_bounds__(256) k_conv(const __hip_bfloat16* __restrict__ bxb,
      const float* __restrict__ cw, const float* __restrict__ cb,
      __hip_bfloat16* __restrict__ xb){
  int r0 = blockIdx.x*32;
  int d = threadIdx.x;
  float w0=cw[d*4], w1=cw[d*4+1], w2=cw[d*4+2], w3=cw[d*4+3], bb=cb[d];
  float a0 = (r0 >= 3) ? __bfloat162float(bxb[(size_t)(r0-3)*256 + d]) : 0.f;
  float a1 = (r0 >= 2) ? __bfloat162float(bxb[(size_t)(r0-2)*256 + d]) : 0.f;
  float a2 = (r0 >= 1) ? __bfloat162float(bxb[(size_t)(r0-1)*256 + d]) : 0.f;
  #pragma unroll 4
  for (int t=0;t<32;t++){
    float a3 = __bfloat162float(bxb[(size_t)(r0+t)*256 + d]);
    float xc = bb + w0*a0 + w1*a1 + w2*a2 + w3*a3;
    xb[(size_t)(r0+t)*256 + d] = __float2bfloat16(siluf_(xc));
    a0=a1; a1=a2; a2=a3;
  }
}

// ---------- K4b: delta = softplus(...), pack (delta | z) -> dzb, coalesced dwords ----------
__global__ void __launch_bounds__(256) k_delta(const float* __restrict__ dt8,
      const float* __restrict__ dtw, const float* __restrict__ dtb,
      const __hip_bfloat16* __restrict__ zb, unsigned* __restrict__ dzb){
  __shared__ float T8[64][8];
  __shared__ float Wd[8][256];
  int r0 = blockIdx.x*64;
  int tid = threadIdx.x;
  for (int e=tid; e<512; e+=256){ int r=e>>3, c=e&7; T8[r][c] = dt8[(size_t)(r0+r)*8 + c]; }
  for (int e=tid; e<2048; e+=256){ int j=e>>8, d=e&255; Wd[j][d] = dtw[j*256 + d]; }
  __syncthreads();
  int d = tid;
  float bb = dtb[d];
  for (int r=0;r<64;r++){
    float acc = bb;
    #pragma unroll
    for (int j=0;j<8;j++) acc += T8[r][j]*Wd[j][d];
    size_t idx = (size_t)(r0+r)*256 + d;
    unsigned zu = *(const unsigned short*)&zb[idx];
    dzb[idx] = f2bfu(softplusf_(acc)) | (zu << 16);
  }
}

// ---------- K5: scan pass 1 — LDS-staged B, dzb lo = delta ----------
__global__ __launch_bounds__(64) void k_scan1(const unsigned* __restrict__ dzb,
      const __hip_bfloat16* __restrict__ xb, const float* __restrict__ Bm,
      const float* __restrict__ A_log, float* __restrict__ dsum_o,
      __hip_bfloat16* __restrict__ Hc){
  __shared__ float Bl[LC][16];
  int g = blockIdx.x;
  int tid = threadIdx.x;
  int d = blockIdx.y*64 + tid;
  int t0 = g*LC;
  ((float4*)&Bl[0][0])[tid] = ((const float4*)(Bm + (size_t)t0*16))[tid];
  __syncthreads();
  float aS[16];
  #pragma unroll
  for (int s=0;s<16;s++) aS[s] = -__expf(A_log[d*16+s]);
  bool fastA = check_intA(aS);
  float h[16] = {};
  float dsum = 0.f;
  if (fastA){
    #pragma unroll 4
    for (int t=0;t<LC;t++){
      unsigned u = dzb[(size_t)(t0+t)*256 + d];
      float dv = bfu2f((unsigned short)(u & 0xffff));
      float xv = __bfloat162float(xb[(size_t)(t0+t)*256 + d]);
      const float4* Bp = (const float4*)&Bl[t][0];
      float4 b0=Bp[0], b1=Bp[1], b2=Bp[2], b3=Bp[3];
      float bl[16] = {b0.x,b0.y,b0.z,b0.w, b1.x,b1.y,b1.z,b1.w,
                      b2.x,b2.y,b2.z,b2.w, b3.x,b3.y,b3.z,b3.w};
      dsum += dv;
      float dx_ = dv*xv;
      float w[16]; pow_chain(__expf(-dv), w);
      #pragma unroll
      for (int s=0;s<16;s++) h[s] = w[s]*h[s] + dx_*bl[s];
    }
  } else {
    #pragma unroll 4
    for (int t=0;t<LC;t++){
      unsigned u = dzb[(size_t)(t0+t)*256 + d];
      float dv = bfu2f((unsigned short)(u & 0xffff));
      float xv = __bfloat162float(xb[(size_t)(t0+t)*256 + d]);
      const float4* Bp = (const float4*)&Bl[t][0];
      float4 b0=Bp[0], b1=Bp[1], b2=Bp[2], b3=Bp[3];
      float bl[16] = {b0.x,b0.y,b0.z,b0.w, b1.x,b1.y,b1.z,b1.w,
                      b2.x,b2.y,b2.z,b2.w, b3.x,b3.y,b3.z,b3.w};
      dsum += dv;
      float dx_ = dv*xv;
      #pragma unroll
      for (int s=0;s<16;s++) h[s] = __expf(dv*aS[s])*h[s] + dx_*bl[s];
    }
  }
  dsum_o[(size_t)g*256 + d] = dsum;
  unsigned u[8];
  #pragma unroll
  for (int q=0;q<8;q++) u[q] = f2bfu(h[2*q]) | (f2bfu(h[2*q+1]) << 16);
  uint4* Hd = (uint4*)(Hc + (size_t)g*4096 + (size_t)d*16);
  Hd[0] = make_uint4(u[0],u[1],u[2],u[3]);
  Hd[1] = make_uint4(u[4],u[5],u[6],u[7]);
}

// ---------- K6a: within-segment prefix (in place on Hc; dsum prefix to dsum_pre) ----------
__global__ __launch_bounds__(256) void k_carry_a(const float* __restrict__ dsum,
      __hip_bfloat16* __restrict__ Hc, const float* __restrict__ A_log,
      float* __restrict__ dsum_pre, float* __restrict__ segsum, float* __restrict__ Hagg){
  int seg = blockIdx.x;
  int ch  = blockIdx.y*256 + threadIdx.x;
  int d = ch>>4, s = ch&15;
  float aSv = -__expf(A_log[ch]);
  float dpre = 0.f, c = 0.f;
  int g0 = seg*SEGLEN;
  #pragma unroll 4
  for (int i=0;i<SEGLEN;i++){
    int g = g0+i;
    float ds = dsum[(size_t)g*256 + d];
    size_t a = (size_t)g*4096 + ch;
    float hh = __bfloat162float(Hc[a]);
    float p = __expf(ds*aSv);
    if (s==0) dsum_pre[(size_t)g*256 + d] = dpre;
    Hc[a] = __float2bfloat16(c);
    dpre += ds;
    c = p*c + hh;
  }
  if (s==0) segsum[seg*256 + d] = dpre;
  Hagg[(size_t)seg*4096 + ch] = c;
}

// ---------- K6b: scan over segment aggregates -> Cseg ----------
__global__ __launch_bounds__(256) void k_carry_b(const float* __restrict__ segsum,
      const float* __restrict__ Hagg, const float* __restrict__ A_log,
      float* __restrict__ Cseg){
  int ch = blockIdx.x*256 + threadIdx.x;
  int d = ch>>4;
  float aSv = -__expf(A_log[ch]);
  float c = 0.f;
  #pragma unroll 8
  for (int s=0;s<NSEG;s++){
    Cseg[(size_t)s*4096 + ch] = c;
    c = __expf(segsum[s*256 + d]*aSv)*c + Hagg[(size_t)s*4096 + ch];
  }
}

// ---------- K7: scan pass 2 — LDS-staged B/C, dzb = (delta|z), gated y (bf16) ----------
__global__ __launch_bounds__(64) void k_scan2(const unsigned* __restrict__ dzb,
      const __hip_bfloat16* __restrict__ xb, const float* __restrict__ Bm,
      const float* __restrict__ Cm, const float* __restrict__ A_log,
      const float* __restrict__ Dp, const float* __restrict__ dsum_pre,
      const __hip_bfloat16* __restrict__ Hc, const float* __restrict__ Cseg,
      __hip_bfloat16* __restrict__ yb){
  __shared__ float Bl[LC][16];
  __shared__ float Cl[LC][16];
  int g = blockIdx.x;
  int tid = threadIdx.x;
  int d = blockIdx.y*64 + tid;
  int t0 = g*LC;
  ((float4*)&Bl[0][0])[tid] = ((const float4*)(Bm + (size_t)t0*16))[tid];
  ((float4*)&Cl[0][0])[tid] = ((const float4*)(Cm + (size_t)t0*16))[tid];
  __syncthreads();
  int seg = g / SEGLEN;
  float aS[16];
  #pragma unroll
  for (int s=0;s<16;s++) aS[s] = -__expf(A_log[d*16+s]);
  bool fastA = check_intA(aS);
  float h[16];
  {
    float dpre = dsum_pre[(size_t)g*256 + d];
    const uint4* hp = (const uint4*)(Hc + (size_t)g*4096 + (size_t)d*16);
    uint4 H0 = hp[0], H1 = hp[1];
    unsigned hu[8] = {H0.x,H0.y,H0.z,H0.w, H1.x,H1.y,H1.z,H1.w};
    const float4* cs = (const float4*)(Cseg + (size_t)seg*4096 + (size_t)d*16);
    float ws[16];
    if (fastA){
      pow_chain(__expf(-dpre), ws);
    } else {
      #pragma unroll
      for (int s=0;s<16;s++) ws[s] = __expf(dpre*aS[s]);
    }
    #pragma unroll
    for (int q=0;q<4;q++){
      float4 C = cs[q];
      h[q*4+0] = ws[q*4+0]*C.x + bfu2f((unsigned short)(hu[q*2]   & 0xffff));
      h[q*4+1] = ws[q*4+1]*C.y + bfu2f((unsigned short)(hu[q*2]   >> 16));
      h[q*4+2] = ws[q*4+2]*C.z + bfu2f((unsigned short)(hu[q*2+1] & 0xffff));
      h[q*4+3] = ws[q*4+3]*C.w + bfu2f((unsigned short)(hu[q*2+1] >> 16));
    }
  }
  float dpar = Dp[d];
  if (fastA){
    #pragma unroll 4
    for (int t=0;t<LC;t++){
      unsigned u = dzb[(size_t)(t0+t)*256 + d];
      float dv = bfu2f((unsigned short)(u & 0xffff));
      float zv = bfu2f((unsigned short)(u >> 16));
      float xv = __bfloat162float(xb[(size_t)(t0+t)*256 + d]);
      const float4* Bp = (const float4*)&Bl[t][0];
      const float4* Cp = (const float4*)&Cl[t][0];
      float4 b0=Bp[0], b1=Bp[1], b2=Bp[2], b3=Bp[3];
      float4 c0=Cp[0], c1=Cp[1], c2=Cp[2], c3=Cp[3];
      float bl[16] = {b0.x,b0.y,b0.z,b0.w, b1.x,b1.y,b1.z,b1.w,
                      b2.x,b2.y,b2.z,b2.w, b3.x,b3.y,b3.z,b3.w};
      float cl[16] = {c0.x,c0.y,c0.z,c0.w, c1.x,c1.y,c1.z,c1.w,
                      c2.x,c2.y,c2.z,c2.w, c3.x,c3.y,c3.z,c3.w};
      float dx_ = dv*xv;
      float w[16]; pow_chain(__expf(-dv), w);
      float yv = 0.f;
      #pragma unroll
      for (int s=0;s<16;s++){
        h[s] = w[s]*h[s] + dx_*bl[s];
        yv += h[s]*cl[s];
      }
      yb[(size_t)(t0+t)*256 + d] = __float2bfloat16((yv + dpar*xv)*zv);
    }
  } else {
    #pragma unroll 4
    for (int t=0;t<LC;t++){
      unsigned u = dzb[(size_t)(t0+t)*256 + d];
      float dv = bfu2f((unsigned short)(u & 0xffff));
      float zv = bfu2f((unsigned short)(u >> 16));
      float xv = __bfloat162float(xb[(size_t)(t0+t)*256 + d]);
      const float4* Bp = (const float4*)&Bl[t][0];
      const float4* Cp = (const float4*)&Cl[t][0];
      float4 b0=Bp[0], b1=Bp[1], b2=Bp[2], b3=Bp[3];
      float4 c0=Cp[0], c1=Cp[1], c2=Cp[2], c3=Cp[3];
      float bl[16] = {b0.x,b0.y,b0.z,b0.w, b1.x,b1.y,b1.z,b1.w,
                      b2.x,b2.y,b2.z,b2.w, b3.x,b3.y,b3.z,b3.w};
      float cl[16] = {c0.x,c0.y,c0.z,c0.w, c1.x,c1.y,c1.z,c1.w,
                      c2.x,c2.y,c2.z,c2.w, c3.x,c3.y,c3.z,c3.w};
      float dx_ = dv*xv;
      float yv = 0.f;
      #pragma unroll
      for (int s=0;s<16;s++){
        h[s] = __expf(dv*aS[s])*h[s] + dx_*bl[s];
        yv += h[s]*cl[s];
      }
      yb[(size_t)(t0+t)*256 + d] = __float2bfloat16((yv + dpar*xv)*zv);
    }
  }
}

extern "C" void kernel_launch(void* const* d_in, const int* in_sizes, int n_in,
                              void* d_out, int out_size, void* d_ws, size_t ws_size,
                              hipStream_t stream){
  const float* feat = (const float*)d_in[0];
  const int*   ridx = (const int*)d_in[2];
  const float* gd   = (const float*)d_in[3];
  const float* ipw  = (const float*)d_in[5];
  const float* cw   = (const float*)d_in[6];
  const float* cb   = (const float*)d_in[7];
  const float* xpw  = (const float*)d_in[8];
  const float* dtw  = (const float*)d_in[9];
  const float* dtb  = (const float*)d_in[10];
  const float* alog = (const float*)d_in[11];
  const float* dpar = (const float*)d_in[12];
  const float* opw  = (const float*)d_in[13];
  const float* rmsw = (const float*)d_in[14];
  const float* lng  = (const float*)d_in[15];
  const float* lnb  = (const float*)d_in[16];
  const float* w1   = (const float*)d_in[17];
  const float* b1   = (const float*)d_in[18];
  const float* lag  = (const float*)d_in[19];
  const float* lab  = (const float*)d_in[20];
  const float* w2   = (const float*)d_in[21];
  const float* b2   = (const float*)d_in[22];
  float* out = (float*)d_out;

  char* p = (char*)d_ws;
  __hip_bfloat16* bxb  = (__hip_bfloat16*)p; p += (size_t)N_TOK*256*2;   // 16MB pre-conv x; h1 later
  __hip_bfloat16* xb   = (__hip_bfloat16*)p; p += (size_t)N_TOK*256*2;   // 16MB silu(conv(x))
  __hip_bfloat16* zb   = (__hip_bfloat16*)p; p += (size_t)N_TOK*256*2;   // 16MB silu(z) contiguous
  unsigned* dzb        = (unsigned*)p;       p += (size_t)N_TOK*256*4;   // 32MB (delta|z) packed
  __hip_bfloat16* cat  = (__hip_bfloat16*)p; p += (size_t)N_TOK*256*2;   // 16MB concat input
  __hip_bfloat16* yb   = (__hip_bfloat16*)p; p += (size_t)N_TOK*256*2;   // 16MB gated y; a0 early
  float* dt8  = (float*)p; p += (size_t)N_TOK*8*4;                       // 1MB
  float* Bm   = (float*)p; p += (size_t)N_TOK*16*4;                      // 2MB
  float* Cm   = (float*)p; p += (size_t)N_TOK*16*4;                      // 2MB
  __hip_bfloat16* Hc = (__hip_bfloat16*)p; p += (size_t)NCHUNK*4096*2;   // 16MB (bf16)
  float* dsum = (float*)p; p += (size_t)NCHUNK*256*4;                    // 2MB
  float* dpre = (float*)p; p += (size_t)NCHUNK*256*4;                    // 2MB
  float* segs = (float*)p; p += (size_t)NSEG*256*4;                      // 64KB
  float* Hagg = (float*)p; p += (size_t)NSEG*4096*4;                     // 1MB
  float* Cseg = (float*)p; p += (size_t)NSEG*4096*4;                     // 1MB
  __hip_bfloat16* ipwt = (__hip_bfloat16*)p; p += 512*128*2;
  __hip_bfloat16* opwt = (__hip_bfloat16*)p; p += 128*256*2;
  __hip_bfloat16* w1t  = (__hip_bfloat16*)p; p += 128*256*2;
  __hip_bfloat16* w2t  = (__hip_bfloat16*)p; p += 128*128*2;
  __hip_bfloat16* xpwt = (__hip_bfloat16*)p; p += 48*256*2;
  __hip_bfloat16* a0 = yb;                     // N*128 bf16, dead before scan2 writes yb
  __hip_bfloat16* h1 = bxb;                    // N*128 bf16, bxb dead after conv

  hipLaunchKernelGGL(k_wcvt_all, dim3(624), dim3(256), 0, stream,
                     ipw, opw, w1, w2, xpw, ipwt, opwt, w1t, w2t, xpwt);
  hipLaunchKernelGGL(k_gat_rms,  dim3(N_TOK/4), dim3(256), 0, stream,
                     feat, ridx, gd, lng, lnb, rmsw, (unsigned*)cat, (unsigned*)a0);
  hipLaunchKernelGGL((k_mfma<4,4,1>), dim3(N_TOK/128, 4), dim3(256), 0, stream,
                     a0, ipwt, 128, (const float*)nullptr, (const float*)nullptr,
                     (float*)nullptr, bxb, zb, 256);
  hipLaunchKernelGGL(k_conv,  dim3(N_TOK/32), dim3(256), 0, stream, bxb, cw, cb, xb);
  hipLaunchKernelGGL(k_xproj_mfma, dim3(N_TOK/64), dim3(256), 0, stream, xb, xpwt, dt8, Bm, Cm);
  hipLaunchKernelGGL(k_delta, dim3(N_TOK/64), dim3(256), 0, stream, dt8, dtw, dtb, zb, dzb);
  hipLaunchKernelGGL(k_scan1, dim3(NCHUNK, 4), dim3(64), 0, stream,
                     dzb, xb, Bm, alog, dsum, Hc);
  hipLaunchKernelGGL(k_carry_a, dim3(NSEG, 16), dim3(256), 0, stream,
                     dsum, Hc, alog, dpre, segs, Hagg);
  hipLaunchKernelGGL(k_carry_b, dim3(16), dim3(256), 0, stream, segs, Hagg, alog, Cseg);
  hipLaunchKernelGGL(k_scan2, dim3(NCHUNK, 4), dim3(64), 0, stream,
                     dzb, xb, Bm, Cm, alog, dpar, dpre, Hc, Cseg, yb);
  hipLaunchKernelGGL((k_mfma_ln<0>), dim3(N_TOK/64), dim3(256), 0, stream,
                     yb, opwt, 256, (const float*)nullptr, feat, lng, lnb,
                     (unsigned*)cat, 128);
  hipLaunchKernelGGL((k_mfma_ln<1>), dim3(N_TOK/64), dim3(256), 0, stream,
                     cat, w1t, 256, b1, (const float*)nullptr, lag, lab,
                     (unsigned*)h1, 64);
  hipLaunchKernelGGL((k_mfma<2,4,0>), dim3(N_TOK/64, 1), dim3(256), 0, stream,
                     h1, w2t, 128, b2, (const float*)nullptr, out,
                     (__hip_bfloat16*)nullptr, (__hip_bfloat16*)nullptr, 128);
}

// Round 14
// 352.201 us; speedup vs baseline: 1.0259x; 1.0259x over previous
//
#include <hip/hip_runtime.h>
#include <hip/hip_bf16.h>
#include <math.h>

#define N_TOK 32768
#define LC 16
#define NCHUNK (N_TOK / LC)   // 2048
#define NSEG 64
#define SEGLEN (NCHUNK / NSEG) // 32

typedef short short8 __attribute__((ext_vector_type(8)));   // 8 bf16 (4 VGPRs)
typedef float f32x4 __attribute__((ext_vector_type(4)));

__device__ __forceinline__ float siluf_(float v){ return v / (1.f + __expf(-v)); }
__device__ __forceinline__ float softplusf_(float v){ return v > 20.f ? v : log1pf(__expf(v)); }

__device__ __forceinline__ unsigned f2bfu(float f){
  __hip_bfloat16 h = __float2bfloat16(f);
  return (unsigned)*(unsigned short*)&h;
}
__device__ __forceinline__ float bfu2f(unsigned short u){
  __hip_bfloat16 h; *(unsigned short*)&h = u; return __bfloat162float(h);
}

__device__ __forceinline__ float waveRed64(float v){
  #pragma unroll
  for (int m = 1; m < 64; m <<= 1) v += __shfl_xor(v, m);
  return v;
}

// pw[s] = w^(s+1), 15 muls, depth 4
__device__ __forceinline__ void pow_chain(float w, float pw[16]){
  pw[0]=w; pw[1]=w*w; pw[2]=pw[1]*w; pw[3]=pw[1]*pw[1];
  pw[4]=pw[3]*pw[0]; pw[5]=pw[3]*pw[1]; pw[6]=pw[3]*pw[2]; pw[7]=pw[3]*pw[3];
  pw[8]=pw[7]*pw[0]; pw[9]=pw[7]*pw[1]; pw[10]=pw[7]*pw[2]; pw[11]=pw[7]*pw[3];
  pw[12]=pw[7]*pw[4]; pw[13]=pw[7]*pw[5]; pw[14]=pw[7]*pw[6]; pw[15]=pw[7]*pw[7];
}

__device__ __forceinline__ bool check_intA(const float aS[16]){
  bool ok = true;
  #pragma unroll
  for (int s=0;s<16;s++){
    float tgt = (float)(s+1);
    if (fabsf(-aS[s] - tgt) > 1e-4f*tgt) ok = false;
  }
  return ok;
}

// ---------- all weight converts in one launch ----------
__global__ void k_wcvt_all(const float* __restrict__ ipw, const float* __restrict__ opw,
                           const float* __restrict__ w1, const float* __restrict__ w2,
                           const float* __restrict__ xpw,
                           __hip_bfloat16* __restrict__ ipwt, __hip_bfloat16* __restrict__ opwt,
                           __hip_bfloat16* __restrict__ w1t, __hip_bfloat16* __restrict__ w2t,
                           __hip_bfloat16* __restrict__ xpwt){
  int e = blockIdx.x*256 + threadIdx.x;
  if (e < 65536){ int n=e>>7, k=e&127; ipwt[e]=__float2bfloat16(ipw[k*512+n]); }
  else if (e < 98304){ int f=e-65536; int n=f>>8, k=f&255; opwt[f]=__float2bfloat16(opw[k*128+n]); }
  else if (e < 131072){ int f=e-98304; int n=f>>8, k=f&255; w1t[f]=__float2bfloat16(w1[k*128+n]); }
  else if (e < 147456){ int f=e-131072; int n=f>>7, k=f&127; w2t[f]=__float2bfloat16(w2[k*128+n]); }
  else if (e < 159744){ int f=e-147456; int n=f>>8, k=f&255;
                        xpwt[f]=(n<40)?__float2bfloat16(xpw[k*40+n]):__float2bfloat16(0.f); }
}

// ---------- K1: fused rmsnorm(feat)->a0 AND gather+LN->cat[:,128:256] ----------
__global__ void k_gat_rms(const float* __restrict__ feat, const int* __restrict__ ridx,
                          const float* __restrict__ gd, const float* __restrict__ g,
                          const float* __restrict__ b, const float* __restrict__ rmsw,
                          unsigned* __restrict__ catu, unsigned* __restrict__ a0u){
  int row = blockIdx.x*4 + (threadIdx.x>>6);
  int lane = threadIdx.x & 63;
  float2 f2 = ((const float2*)feat)[row*64 + lane];
  float ss = waveRed64(f2.x*f2.x + f2.y*f2.y);
  float is0 = rsqrtf(ss * (1.f/128.f) + 1e-5f);
  float2 w = ((const float2*)rmsw)[lane];
  a0u[row*64 + lane] = f2bfu(f2.x*is0*w.x) | (f2bfu(f2.y*is0*w.y) << 16);
  float ax=0.f, ay=0.f;
  #pragma unroll 4
  for (int k=0;k<16;k++){
    int idx = ridx[row*16+k];
    float ww = gd[row*16+k];
    float2 f = ((const float2*)feat)[idx*64 + lane];
    ax += ww*f.x; ay += ww*f.y;
  }
  float m = waveRed64(ax+ay) * (1.f/128.f);
  float dx = ax-m, dy = ay-m;
  float var = waveRed64(dx*dx+dy*dy) * (1.f/128.f);
  float is = rsqrtf(var + 1e-5f);
  float2 gg = ((const float2*)g)[lane];
  float2 bb = ((const float2*)b)[lane];
  float ox = dx*is*gg.x + bb.x, oy = dy*is*gg.y + bb.y;
  catu[row*128 + 64 + lane] = f2bfu(ox) | (f2bfu(oy) << 16);
}

// ---------- MFMA GEMM: out[M,N] = A[M,K](bf16) @ Wt[N,K](bf16)^T ----------
// MODE 0: + bias? + resid? -> out0 (f32)
// MODE 1: n<256 -> out0b (x, bf16); n>=256 -> silu -> out1 (z, bf16 contiguous)
template<int WM16, int WN16, int MODE>
__global__ __launch_bounds__(256) void k_mfma(const __hip_bfloat16* __restrict__ A,
      const __hip_bfloat16* __restrict__ Wt, int K,
      const float* __restrict__ bias, const float* __restrict__ resid,
      float* __restrict__ out0, __hip_bfloat16* __restrict__ out0b,
      __hip_bfloat16* __restrict__ out1, int ldout){
  int tid = threadIdx.x;
  int wave = tid>>6, lane = tid&63;
  int wm = wave>>1, wn = wave&1;
  int lane16 = lane&15, quad = lane>>4;
  int m_w = blockIdx.x*(2*WM16*16) + wm*(WM16*16);
  int n_w = blockIdx.y*(2*WN16*16) + wn*(WN16*16);
  f32x4 acc[WM16][WN16];
  #pragma unroll
  for (int i=0;i<WM16;i++)
    #pragma unroll
    for (int j=0;j<WN16;j++) acc[i][j] = (f32x4){0.f,0.f,0.f,0.f};
  const __hip_bfloat16* Ab = A  + (size_t)(m_w + lane16)*K + quad*8;
  const __hip_bfloat16* Bb = Wt + (size_t)(n_w + lane16)*K + quad*8;
  #pragma unroll 4
  for (int kk=0; kk<K; kk+=32){
    short8 a[WM16], b[WN16];
    #pragma unroll
    for (int i=0;i<WM16;i++) a[i] = *(const short8*)(Ab + (size_t)i*16*K + kk);
    #pragma unroll
    for (int j=0;j<WN16;j++) b[j] = *(const short8*)(Bb + (size_t)j*16*K + kk);
    #pragma unroll
    for (int i=0;i<WM16;i++)
      #pragma unroll
      for (int j=0;j<WN16;j++)
        acc[i][j] = __builtin_amdgcn_mfma_f32_16x16x32_bf16(a[i], b[j], acc[i][j], 0, 0, 0);
  }
  #pragma unroll
  for (int i=0;i<WM16;i++){
    #pragma unroll
    for (int j=0;j<WN16;j++){
      int n = n_w + j*16 + lane16;
      float bv = 0.f;
      if (MODE==0 && bias) bv = bias[n];
      #pragma unroll
      for (int r=0;r<4;r++){
        int m = m_w + i*16 + quad*4 + r;
        float v = acc[i][j][r] + bv;
        if (MODE==0){
          if (resid) v += resid[(size_t)m*ldout + n];
          out0[(size_t)m*ldout + n] = v;
        } else {
          if (n < 256) out0b[(size_t)m*256 + n] = __float2bfloat16(v);
          else         out1[(size_t)m*256 + (n-256)] = __float2bfloat16(siluf_(v));
        }
      }
    }
  }
}

// ---------- fused MFMA + LayerNorm: tile 64x128 -> LDS -> rowwise LN -> bf16 ----------
template<int RELU>
__global__ __launch_bounds__(256) void k_mfma_ln(const __hip_bfloat16* __restrict__ A,
      const __hip_bfloat16* __restrict__ Wt, int K,
      const float* __restrict__ bias, const float* __restrict__ resid,
      const float* __restrict__ g, const float* __restrict__ b,
      unsigned* __restrict__ outu, int ldu){
  __shared__ float Ls[64][132];
  int tid = threadIdx.x;
  int wave = tid>>6, lane = tid&63;
  int wm = wave>>1, wn = wave&1;
  int lane16 = lane&15, quad = lane>>4;
  int r0 = blockIdx.x*64;
  int m_w = wm*32;
  int n_w = wn*64;
  f32x4 acc[2][4];
  #pragma unroll
  for (int i=0;i<2;i++)
    #pragma unroll
    for (int j=0;j<4;j++) acc[i][j] = (f32x4){0.f,0.f,0.f,0.f};
  const __hip_bfloat16* Ab = A  + (size_t)(r0 + m_w + lane16)*K + quad*8;
  const __hip_bfloat16* Bb = Wt + (size_t)(n_w + lane16)*K + quad*8;
  #pragma unroll 4
  for (int kk=0; kk<K; kk+=32){
    short8 a[2], bfr[4];
    #pragma unroll
    for (int i=0;i<2;i++) a[i] = *(const short8*)(Ab + (size_t)i*16*K + kk);
    #pragma unroll
    for (int j=0;j<4;j++) bfr[j] = *(const short8*)(Bb + (size_t)j*16*K + kk);
    #pragma unroll
    for (int i=0;i<2;i++)
      #pragma unroll
      for (int j=0;j<4;j++)
        acc[i][j] = __builtin_amdgcn_mfma_f32_16x16x32_bf16(a[i], bfr[j], acc[i][j], 0, 0, 0);
  }
  #pragma unroll
  for (int i=0;i<2;i++){
    #pragma unroll
    for (int j=0;j<4;j++){
      int n = n_w + j*16 + lane16;
      float bv = bias ? bias[n] : 0.f;
      #pragma unroll
      for (int r=0;r<4;r++){
        int m = m_w + i*16 + quad*4 + r;
        float v = acc[i][j][r] + bv;
        if (resid) v += resid[(size_t)(r0+m)*128 + n];
        Ls[m][n] = v;
      }
    }
  }
  __syncthreads();
  float2 gv = ((const float2*)g)[lane];
  float2 bv2 = ((const float2*)b)[lane];
  #pragma unroll 4
  for (int rr=0; rr<16; rr++){
    int row = wave*16 + rr;
    float2 v = *(const float2*)&Ls[row][2*lane];
    float mm = waveRed64(v.x+v.y) * (1.f/128.f);
    float dx = v.x-mm, dy = v.y-mm;
    float var = waveRed64(dx*dx+dy*dy) * (1.f/128.f);
    float is = rsqrtf(var + 1e-5f);
    float ox = dx*is*gv.x + bv2.x;
    float oy = dy*is*gv.y + bv2.y;
    if (RELU){ ox = fmaxf(ox, 0.f); oy = fmaxf(oy, 0.f); }
    outu[(size_t)(r0+row)*ldu + lane] = f2bfu(ox) | (f2bfu(oy) << 16);
  }
}

// ---------- xproj MFMA: dbc[M,48] = xb[M,256] @ xpwt[48,256]^T, split-store ----------
__global__ __launch_bounds__(256) void k_xproj_mfma(const __hip_bfloat16* __restrict__ A,
      const __hip_bfloat16* __restrict__ Wt,
      float* __restrict__ dt8, float* __restrict__ Bm, float* __restrict__ Cm){
  int tid = threadIdx.x;
  int wave = tid>>6, lane = tid&63;
  int lane16 = lane&15, quad = lane>>4;
  int m_w = blockIdx.x*64 + wave*16;
  f32x4 acc[3];
  #pragma unroll
  for (int j=0;j<3;j++) acc[j] = (f32x4){0.f,0.f,0.f,0.f};
  const __hip_bfloat16* Ab = A  + (size_t)(m_w + lane16)*256 + quad*8;
  const __hip_bfloat16* Bb = Wt + (size_t)lane16*256 + quad*8;
  #pragma unroll
  for (int kk=0; kk<256; kk+=32){
    short8 a = *(const short8*)(Ab + kk);
    short8 b0 = *(const short8*)(Bb + kk);
    short8 b1 = *(const short8*)(Bb + 16*256 + kk);
    short8 b2 = *(const short8*)(Bb + 32*256 + kk);
    acc[0] = __builtin_amdgcn_mfma_f32_16x16x32_bf16(a, b0, acc[0], 0, 0, 0);
    acc[1] = __builtin_amdgcn_mfma_f32_16x16x32_bf16(a, b1, acc[1], 0, 0, 0);
    acc[2] = __builtin_amdgcn_mfma_f32_16x16x32_bf16(a, b2, acc[2], 0, 0, 0);
  }
  #pragma unroll
  for (int j=0;j<3;j++){
    int n = j*16 + lane16;
    #pragma unroll
    for (int r=0;r<4;r++){
      int m = m_w + quad*4 + r;
      float v = acc[j][r];
      if (n < 8)       dt8[(size_t)m*8 + n] = v;
      else if (n < 24) Bm[(size_t)m*16 + (n-8)] = v;
      else if (n < 40) Cm[(size_t)m*16 + (n-24)] = v;
    }
  }
}

// ---------- K3: causal depthwise conv + silu, bf16 in/out ----------
__global__ void __launch_bounds__(256) k_conv(const __hip_bfloat16* __restrict__ bxb,
      const float* __restrict__ cw, const float* __restrict__ cb,
      __hip_bfloat16* __restrict__ xb){
  int r0 = blockIdx.x*32;
  int d = threadIdx.x;
  float w0=cw[d*4], w1=cw[d*4+1], w2=cw[d*4+2], w3=cw[d*4+3], bb=cb[d];
  float a0 = (r0 >= 3) ? __bfloat162float(bxb[(size_t)(r0-3)*256 + d]) : 0.f;
  float a1 = (r0 >= 2) ? __bfloat162float(bxb[(size_t)(r0-2)*256 + d]) : 0.f;
  float a2 = (r0 >= 1) ? __bfloat162float(bxb[(size_t)(r0-1)*256 + d]) : 0.f;
  #pragma unroll 4
  for (int t=0;t<32;t++){
    float a3 = __bfloat162float(bxb[(size_t)(r0+t)*256 + d]);
    float xc = bb + w0*a0 + w1*a1 + w2*a2 + w3*a3;
    xb[(size_t)(r0+t)*256 + d] = __float2bfloat16(siluf_(xc));
    a0=a1; a1=a2; a2=a3;
  }
}

// ---------- K4b: one block per row, one elem per thread — streaming pack ----------
__global__ void __launch_bounds__(256) k_delta(const float* __restrict__ dt8,
      const float* __restrict__ dtw, const float* __restrict__ dtb,
      const __hip_bfloat16* __restrict__ zb, unsigned* __restrict__ dzb){
  int row = blockIdx.x;
  int d = threadIdx.x;
  const float4* T = (const float4*)(dt8 + (size_t)row*8);
  float4 u = T[0], v = T[1];                 // wave-uniform (L1 broadcast)
  float acc = dtb[d]
    + u.x*dtw[0*256+d] + u.y*dtw[1*256+d] + u.z*dtw[2*256+d] + u.w*dtw[3*256+d]
    + v.x*dtw[4*256+d] + v.y*dtw[5*256+d] + v.z*dtw[6*256+d] + v.w*dtw[7*256+d];
  size_t idx = (size_t)row*256 + d;
  unsigned zu = *(const unsigned short*)&zb[idx];
  dzb[idx] = f2bfu(softplusf_(acc)) | (zu << 16);
}

// ---------- K5: scan pass 1 — LDS-staged B, dzb lo = delta ----------
__global__ __launch_bounds__(64) void k_scan1(const unsigned* __restrict__ dzb,
      const __hip_bfloat16* __restrict__ xb, const float* __restrict__ Bm,
      const float* __restrict__ A_log, float* __restrict__ dsum_o,
      __hip_bfloat16* __restrict__ Hc){
  __shared__ float Bl[LC][16];
  int g = blockIdx.x;
  int tid = threadIdx.x;
  int d = blockIdx.y*64 + tid;
  int t0 = g*LC;
  ((float4*)&Bl[0][0])[tid] = ((const float4*)(Bm + (size_t)t0*16))[tid];
  __syncthreads();
  float aS[16];
  #pragma unroll
  for (int s=0;s<16;s++) aS[s] = -__expf(A_log[d*16+s]);
  bool fastA = check_intA(aS);
  float h[16] = {};
  float dsum = 0.f;
  if (fastA){
    #pragma unroll 4
    for (int t=0;t<LC;t++){
      unsigned u = dzb[(size_t)(t0+t)*256 + d];
      float dv = bfu2f((unsigned short)(u & 0xffff));
      float xv = __bfloat162float(xb[(size_t)(t0+t)*256 + d]);
      const float4* Bp = (const float4*)&Bl[t][0];
      float4 b0=Bp[0], b1=Bp[1], b2=Bp[2], b3=Bp[3];
      float bl[16] = {b0.x,b0.y,b0.z,b0.w, b1.x,b1.y,b1.z,b1.w,
                      b2.x,b2.y,b2.z,b2.w, b3.x,b3.y,b3.z,b3.w};
      dsum += dv;
      float dx_ = dv*xv;
      float w[16]; pow_chain(__expf(-dv), w);
      #pragma unroll
      for (int s=0;s<16;s++) h[s] = w[s]*h[s] + dx_*bl[s];
    }
  } else {
    #pragma unroll 4
    for (int t=0;t<LC;t++){
      unsigned u = dzb[(size_t)(t0+t)*256 + d];
      float dv = bfu2f((unsigned short)(u & 0xffff));
      float xv = __bfloat162float(xb[(size_t)(t0+t)*256 + d]);
      const float4* Bp = (const float4*)&Bl[t][0];
      float4 b0=Bp[0], b1=Bp[1], b2=Bp[2], b3=Bp[3];
      float bl[16] = {b0.x,b0.y,b0.z,b0.w, b1.x,b1.y,b1.z,b1.w,
                      b2.x,b2.y,b2.z,b2.w, b3.x,b3.y,b3.z,b3.w};
      dsum += dv;
      float dx_ = dv*xv;
      #pragma unroll
      for (int s=0;s<16;s++) h[s] = __expf(dv*aS[s])*h[s] + dx_*bl[s];
    }
  }
  dsum_o[(size_t)g*256 + d] = dsum;
  unsigned u[8];
  #pragma unroll
  for (int q=0;q<8;q++) u[q] = f2bfu(h[2*q]) | (f2bfu(h[2*q+1]) << 16);
  uint4* Hd = (uint4*)(Hc + (size_t)g*4096 + (size_t)d*16);
  Hd[0] = make_uint4(u[0],u[1],u[2],u[3]);
  Hd[1] = make_uint4(u[4],u[5],u[6],u[7]);
}

// ---------- K6a: within-segment prefix (in place on Hc; dsum prefix to dsum_pre) ----------
__global__ __launch_bounds__(256) void k_carry_a(const float* __restrict__ dsum,
      __hip_bfloat16* __restrict__ Hc, const float* __restrict__ A_log,
      float* __restrict__ dsum_pre, float* __restrict__ segsum, float* __restrict__ Hagg){
  int seg = blockIdx.x;
  int ch  = blockIdx.y*256 + threadIdx.x;
  int d = ch>>4, s = ch&15;
  float aSv = -__expf(A_log[ch]);
  float dpre = 0.f, c = 0.f;
  int g0 = seg*SEGLEN;
  #pragma unroll 4
  for (int i=0;i<SEGLEN;i++){
    int g = g0+i;
    float ds = dsum[(size_t)g*256 + d];
    size_t a = (size_t)g*4096 + ch;
    float hh = __bfloat162float(Hc[a]);
    float p = __expf(ds*aSv);
    if (s==0) dsum_pre[(size_t)g*256 + d] = dpre;
    Hc[a] = __float2bfloat16(c);
    dpre += ds;
    c = p*c + hh;
  }
  if (s==0) segsum[seg*256 + d] = dpre;
  Hagg[(size_t)seg*4096 + ch] = c;
}

// ---------- K6b: scan over segment aggregates -> Cseg ----------
__global__ __launch_bounds__(256) void k_carry_b(const float* __restrict__ segsum,
      const float* __restrict__ Hagg, const float* __restrict__ A_log,
      float* __restrict__ Cseg){
  int ch = blockIdx.x*256 + threadIdx.x;
  int d = ch>>4;
  float aSv = -__expf(A_log[ch]);
  float c = 0.f;
  #pragma unroll 8
  for (int s=0;s<NSEG;s++){
    Cseg[(size_t)s*4096 + ch] = c;
    c = __expf(segsum[s*256 + d]*aSv)*c + Hagg[(size_t)s*4096 + ch];
  }
}

// ---------- K7: scan pass 2 — LDS-staged B/C, dzb = (delta|z), gated y (bf16) ----------
__global__ __launch_bounds__(64) void k_scan2(const unsigned* __restrict__ dzb,
      const __hip_bfloat16* __restrict__ xb, const float* __restrict__ Bm,
      const float* __restrict__ Cm, const float* __restrict__ A_log,
      const float* __restrict__ Dp, const float* __restrict__ dsum_pre,
      const __hip_bfloat16* __restrict__ Hc, const float* __restrict__ Cseg,
      __hip_bfloat16* __restrict__ yb){
  __shared__ float Bl[LC][16];
  __shared__ float Cl[LC][16];
  int g = blockIdx.x;
  int tid = threadIdx.x;
  int d = blockIdx.y*64 + tid;
  int t0 = g*LC;
  ((float4*)&Bl[0][0])[tid] = ((const float4*)(Bm + (size_t)t0*16))[tid];
  ((float4*)&Cl[0][0])[tid] = ((const float4*)(Cm + (size_t)t0*16))[tid];
  __syncthreads();
  int seg = g / SEGLEN;
  float aS[16];
  #pragma unroll
  for (int s=0;s<16;s++) aS[s] = -__expf(A_log[d*16+s]);
  bool fastA = check_intA(aS);
  float h[16];
  {
    float dpre = dsum_pre[(size_t)g*256 + d];
    const uint4* hp = (const uint4*)(Hc + (size_t)g*4096 + (size_t)d*16);
    uint4 H0 = hp[0], H1 = hp[1];
    unsigned hu[8] = {H0.x,H0.y,H0.z,H0.w, H1.x,H1.y,H1.z,H1.w};
    const float4* cs = (const float4*)(Cseg + (size_t)seg*4096 + (size_t)d*16);
    float ws[16];
    if (fastA){
      pow_chain(__expf(-dpre), ws);
    } else {
      #pragma unroll
      for (int s=0;s<16;s++) ws[s] = __expf(dpre*aS[s]);
    }
    #pragma unroll
    for (int q=0;q<4;q++){
      float4 C = cs[q];
      h[q*4+0] = ws[q*4+0]*C.x + bfu2f((unsigned short)(hu[q*2]   & 0xffff));
      h[q*4+1] = ws[q*4+1]*C.y + bfu2f((unsigned short)(hu[q*2]   >> 16));
      h[q*4+2] = ws[q*4+2]*C.z + bfu2f((unsigned short)(hu[q*2+1] & 0xffff));
      h[q*4+3] = ws[q*4+3]*C.w + bfu2f((unsigned short)(hu[q*2+1] >> 16));
    }
  }
  float dpar = Dp[d];
  if (fastA){
    #pragma unroll 4
    for (int t=0;t<LC;t++){
      unsigned u = dzb[(size_t)(t0+t)*256 + d];
      float dv = bfu2f((unsigned short)(u & 0xffff));
      float zv = bfu2f((unsigned short)(u >> 16));
      float xv = __bfloat162float(xb[(size_t)(t0+t)*256 + d]);
      const float4* Bp = (const float4*)&Bl[t][0];
      const float4* Cp = (const float4*)&Cl[t][0];
      float4 b0=Bp[0], b1=Bp[1], b2=Bp[2], b3=Bp[3];
      float4 c0=Cp[0], c1=Cp[1], c2=Cp[2], c3=Cp[3];
      float bl[16] = {b0.x,b0.y,b0.z,b0.w, b1.x,b1.y,b1.z,b1.w,
                      b2.x,b2.y,b2.z,b2.w, b3.x,b3.y,b3.z,b3.w};
      float cl[16] = {c0.x,c0.y,c0.z,c0.w, c1.x,c1.y,c1.z,c1.w,
                      c2.x,c2.y,c2.z,c2.w, c3.x,c3.y,c3.z,c3.w};
      float dx_ = dv*xv;
      float w[16]; pow_chain(__expf(-dv), w);
      float yv = 0.f;
      #pragma unroll
      for (int s=0;s<16;s++){
        h[s] = w[s]*h[s] + dx_*bl[s];
        yv += h[s]*cl[s];
      }
      yb[(size_t)(t0+t)*256 + d] = __float2bfloat16((yv + dpar*xv)*zv);
    }
  } else {
    #pragma unroll 4
    for (int t=0;t<LC;t++){
      unsigned u = dzb[(size_t)(t0+t)*256 + d];
      float dv = bfu2f((unsigned short)(u & 0xffff));
      float zv = bfu2f((unsigned short)(u >> 16));
      float xv = __bfloat162float(xb[(size_t)(t0+t)*256 + d]);
      const float4* Bp = (const float4*)&Bl[t][0];
      const float4* Cp = (const float4*)&Cl[t][0];
      float4 b0=Bp[0], b1=Bp[1], b2=Bp[2], b3=Bp[3];
      float4 c0=Cp[0], c1=Cp[1], c2=Cp[2], c3=Cp[3];
      float bl[16] = {b0.x,b0.y,b0.z,b0.w, b1.x,b1.y,b1.z,b1.w,
                      b2.x,b2.y,b2.z,b2.w, b3.x,b3.y,b3.z,b3.w};
      float cl[16] = {c0.x,c0.y,c0.z,c0.w, c1.x,c1.y,c1.z,c1.w,
                      c2.x,c2.y,c2.z,c2.w, c3.x,c3.y,c3.z,c3.w};
      float dx_ = dv*xv;
      float yv = 0.f;
      #pragma unroll
      for (int s=0;s<16;s++){
        h[s] = __expf(dv*aS[s])*h[s] + dx_*bl[s];
        yv += h[s]*cl[s];
      }
      yb[(size_t)(t0+t)*256 + d] = __float2bfloat16((yv + dpar*xv)*zv);
    }
  }
}

extern "C" void kernel_launch(void* const* d_in, const int* in_sizes, int n_in,
                              void* d_out, int out_size, void* d_ws, size_t ws_size,
                              hipStream_t stream){
  const float* feat = (const float*)d_in[0];
  const int*   ridx = (const int*)d_in[2];
  const float* gd   = (const float*)d_in[3];
  const float* ipw  = (const float*)d_in[5];
  const float* cw   = (const float*)d_in[6];
  const float* cb   = (const float*)d_in[7];
  const float* xpw  = (const float*)d_in[8];
  const float* dtw  = (const float*)d_in[9];
  const float* dtb  = (const float*)d_in[10];
  const float* alog = (const float*)d_in[11];
  const float* dpar = (const float*)d_in[12];
  const float* opw  = (const float*)d_in[13];
  const float* rmsw = (const float*)d_in[14];
  const float* lng  = (const float*)d_in[15];
  const float* lnb  = (const float*)d_in[16];
  const float* w1   = (const float*)d_in[17];
  const float* b1   = (const float*)d_in[18];
  const float* lag  = (const float*)d_in[19];
  const float* lab  = (const float*)d_in[20];
  const float* w2   = (const float*)d_in[21];
  const float* b2   = (const float*)d_in[22];
  float* out = (float*)d_out;

  char* p = (char*)d_ws;
  __hip_bfloat16* bxb  = (__hip_bfloat16*)p; p += (size_t)N_TOK*256*2;   // 16MB pre-conv x; h1 later
  __hip_bfloat16* xb   = (__hip_bfloat16*)p; p += (size_t)N_TOK*256*2;   // 16MB silu(conv(x))
  __hip_bfloat16* zb   = (__hip_bfloat16*)p; p += (size_t)N_TOK*256*2;   // 16MB silu(z) contiguous
  unsigned* dzb        = (unsigned*)p;       p += (size_t)N_TOK*256*4;   // 32MB (delta|z) packed
  __hip_bfloat16* cat  = (__hip_bfloat16*)p; p += (size_t)N_TOK*256*2;   // 16MB concat input
  __hip_bfloat16* yb   = (__hip_bfloat16*)p; p += (size_t)N_TOK*256*2;   // 16MB gated y; a0 early
  float* dt8  = (float*)p; p += (size_t)N_TOK*8*4;                       // 1MB
  float* Bm   = (float*)p; p += (size_t)N_TOK*16*4;                      // 2MB
  float* Cm   = (float*)p; p += (size_t)N_TOK*16*4;                      // 2MB
  __hip_bfloat16* Hc = (__hip_bfloat16*)p; p += (size_t)NCHUNK*4096*2;   // 16MB (bf16)
  float* dsum = (float*)p; p += (size_t)NCHUNK*256*4;                    // 2MB
  float* dpre = (float*)p; p += (size_t)NCHUNK*256*4;                    // 2MB
  float* segs = (float*)p; p += (size_t)NSEG*256*4;                      // 64KB
  float* Hagg = (float*)p; p += (size_t)NSEG*4096*4;                     // 1MB
  float* Cseg = (float*)p; p += (size_t)NSEG*4096*4;                     // 1MB
  __hip_bfloat16* ipwt = (__hip_bfloat16*)p; p += 512*128*2;
  __hip_bfloat16* opwt = (__hip_bfloat16*)p; p += 128*256*2;
  __hip_bfloat16* w1t  = (__hip_bfloat16*)p; p += 128*256*2;
  __hip_bfloat16* w2t  = (__hip_bfloat16*)p; p += 128*128*2;
  __hip_bfloat16* xpwt = (__hip_bfloat16*)p; p += 48*256*2;
  __hip_bfloat16* a0 = yb;                     // N*128 bf16, dead before scan2 writes yb
  __hip_bfloat16* h1 = bxb;                    // N*128 bf16, bxb dead after conv

  hipLaunchKernelGGL(k_wcvt_all, dim3(624), dim3(256), 0, stream,
                     ipw, opw, w1, w2, xpw, ipwt, opwt, w1t, w2t, xpwt);
  hipLaunchKernelGGL(k_gat_rms,  dim3(N_TOK/4), dim3(256), 0, stream,
                     feat, ridx, gd, lng, lnb, rmsw, (unsigned*)cat, (unsigned*)a0);
  hipLaunchKernelGGL((k_mfma<4,4,1>), dim3(N_TOK/128, 4), dim3(256), 0, stream,
                     a0, ipwt, 128, (const float*)nullptr, (const float*)nullptr,
                     (float*)nullptr, bxb, zb, 256);
  hipLaunchKernelGGL(k_conv,  dim3(N_TOK/32), dim3(256), 0, stream, bxb, cw, cb, xb);
  hipLaunchKernelGGL(k_xproj_mfma, dim3(N_TOK/64), dim3(256), 0, stream, xb, xpwt, dt8, Bm, Cm);
  hipLaunchKernelGGL(k_delta, dim3(N_TOK), dim3(256), 0, stream, dt8, dtw, dtb, zb, dzb);
  hipLaunchKernelGGL(k_scan1, dim3(NCHUNK, 4), dim3(64), 0, stream,
                     dzb, xb, Bm, alog, dsum, Hc);
  hipLaunchKernelGGL(k_carry_a, dim3(NSEG, 16), dim3(256), 0, stream,
                     dsum, Hc, alog, dpre, segs, Hagg);
  hipLaunchKernelGGL(k_carry_b, dim3(16), dim3(256), 0, stream, segs, Hagg, alog, Cseg);
  hipLaunchKernelGGL(k_scan2, dim3(NCHUNK, 4), dim3(64), 0, stream,
                     dzb, xb, Bm, Cm, alog, dpar, dpre, Hc, Cseg, yb);
  hipLaunchKernelGGL((k_mfma_ln<0>), dim3(N_TOK/64), dim3(256), 0, stream,
                     yb, opwt, 256, (const float*)nullptr, feat, lng, lnb,
                     (unsigned*)cat, 128);
  hipLaunchKernelGGL((k_mfma_ln<1>), dim3(N_TOK/64), dim3(256), 0, stream,
                     cat, w1t, 256, b1, (const float*)nullptr, lag, lab,
                     (unsigned*)h1, 64);
  hipLaunchKernelGGL((k_mfma<2,4,0>), dim3(N_TOK/64, 1), dim3(256), 0, stream,
                     h1, w2t, 128, b2, (const float*)nullptr, out,
                     (__hip_bfloat16*)nullptr, (__hip_bfloat16*)nullptr, 128);
}